// Round 5
// baseline (284.741 us; speedup 1.0000x reference)
//
#include <hip/hip_runtime.h>
#include <math.h>

#define NN 325
#define BT 96
#define NROWS (BT * NN)   // 31200
// fold softmax scale and log2(e) into q: exp(s/sqrt8) == exp2(s * SCL)
#define SCL (0.35355339059327373f * 1.4426950408889634f)

__device__ __forceinline__ float gelu_f(float x) {
    return 0.5f * x * (1.0f + erff(x * 0.70710678118654752f));
}

// ---------------------------------------------------------------------------
// Kernel 0: pack adj into transposed bitmasks: packedT[w*NN + n] holds bits
// for columns m = 32w..32w+31 of row n. Bits for m >= NN are 0.
// ---------------------------------------------------------------------------
__global__ void pack_adj_kernel(const int* __restrict__ adj,
                                unsigned int* __restrict__ packedT)
{
    int idx = blockIdx.x * 256 + threadIdx.x;
    if (idx >= 11 * NN) return;
    int w = idx / NN, n = idx - w * NN;
    unsigned int bits = 0u;
    #pragma unroll 8
    for (int j = 0; j < 32; ++j) {
        int m = w * 32 + j;
        if (m < NN && adj[n * NN + m] > 0) bits |= (1u << j);
    }
    packedT[w * NN + n] = bits;
}

// ---------------------------------------------------------------------------
// Kernel 1: q/k/v = gelu(concat(X,STE) @ W.T + b).  64-row tiles, 128 thr.
// Thread = 8 rows x 4 cols (32 FMA per 3 ds_read_b128).  xsT/wsT transposed
// (stride 68 floats = 16B-aligned, 2-way bank alias only).
// ---------------------------------------------------------------------------
__device__ __forceinline__ void qkv_phase(
    const float* __restrict__ W, const float* __restrict__ b,
    float* __restrict__ outp, const float* xsT, float* wsT,
    int tid, int row0, int rg8, int cg4)
{
    __syncthreads();   // wsT reuse between phases
    #pragma unroll 4
    for (int idx = tid; idx < 64 * 128; idx += 128) {
        int c = idx >> 7, i = idx & 127;
        wsT[i * 68 + c] = W[idx];          // W[c][i] -> wsT[i][c]
    }
    __syncthreads();

    float acc[8][4];
    const float4 bias = *(const float4*)(b + cg4);
    #pragma unroll
    for (int rr = 0; rr < 8; ++rr) {
        acc[rr][0] = bias.x; acc[rr][1] = bias.y;
        acc[rr][2] = bias.z; acc[rr][3] = bias.w;
    }

    #pragma unroll 4
    for (int i = 0; i < 128; ++i) {
        float4 w  = *(const float4*)&wsT[i * 68 + cg4];
        float4 x0 = *(const float4*)&xsT[i * 68 + rg8];
        float4 x1 = *(const float4*)&xsT[i * 68 + rg8 + 4];
        const float xr[8] = {x0.x, x0.y, x0.z, x0.w, x1.x, x1.y, x1.z, x1.w};
        #pragma unroll
        for (int rr = 0; rr < 8; ++rr) {
            acc[rr][0] = fmaf(xr[rr], w.x, acc[rr][0]);
            acc[rr][1] = fmaf(xr[rr], w.y, acc[rr][1]);
            acc[rr][2] = fmaf(xr[rr], w.z, acc[rr][2]);
            acc[rr][3] = fmaf(xr[rr], w.w, acc[rr][3]);
        }
    }

    #pragma unroll
    for (int rr = 0; rr < 8; ++rr) {
        int R = row0 + rg8 + rr;
        if (R < NROWS) {
            float4 g;
            g.x = gelu_f(acc[rr][0]); g.y = gelu_f(acc[rr][1]);
            g.z = gelu_f(acc[rr][2]); g.w = gelu_f(acc[rr][3]);
            *(float4*)&outp[R * 64 + cg4] = g;
        }
    }
}

__global__ __launch_bounds__(128) void qkv_kernel(
    const float* __restrict__ X, const float* __restrict__ STE,
    const float* __restrict__ W7, const float* __restrict__ b7,
    const float* __restrict__ W8, const float* __restrict__ b8,
    const float* __restrict__ W9, const float* __restrict__ b9,
    float* __restrict__ q, float* __restrict__ k, float* __restrict__ v)
{
    __shared__ float xsT[128 * 68];   // [i][r], 34.8 KB
    __shared__ float wsT[128 * 68];   // [i][c], 34.8 KB (reused per phase)
    const int tid  = threadIdx.x;
    const int row0 = blockIdx.x * 64;

    #pragma unroll 4
    for (int idx = tid; idx < 64 * 128; idx += 128) {
        int r = idx >> 7, i = idx & 127;
        int R = row0 + r;
        float val = 0.0f;
        if (R < NROWS)
            val = (i < 64) ? X[R * 64 + i] : STE[R * 64 + (i - 64)];
        xsT[i * 68 + r] = val;
    }

    const int cg4 = (tid & 15) * 4;
    const int rg8 = (tid >> 4) * 8;

    qkv_phase(W7, b7, q, xsT, wsT, tid, row0, rg8, cg4);
    qkv_phase(W8, b8, k, xsT, wsT, tid, row0, rg8, cg4);
    qkv_phase(W9, b9, v, xsT, wsT, tid, row0, rg8, cg4);
}

// ---------------------------------------------------------------------------
// Kernel 2: attention.  One 128-thread block per (bt,h); 3 rows/lane
// (n = tid, tid+128, tid+256) -> kv broadcast reads amortized over 3 rows.
// K/V interleaved kv[m][16] in LDS; exp2-domain softmax, masked p = 0.
// ---------------------------------------------------------------------------
__device__ __forceinline__ float dot8(const float* qr, float4 a, float4 b) {
    float s = qr[0] * a.x;
    s = fmaf(qr[1], a.y, s); s = fmaf(qr[2], a.z, s); s = fmaf(qr[3], a.w, s);
    s = fmaf(qr[4], b.x, s); s = fmaf(qr[5], b.y, s);
    s = fmaf(qr[6], b.z, s); s = fmaf(qr[7], b.w, s);
    return s;
}

__device__ __forceinline__ void pv8(float* acc, float p, float4 a, float4 b) {
    acc[0] = fmaf(p, a.x, acc[0]); acc[1] = fmaf(p, a.y, acc[1]);
    acc[2] = fmaf(p, a.z, acc[2]); acc[3] = fmaf(p, a.w, acc[3]);
    acc[4] = fmaf(p, b.x, acc[4]); acc[5] = fmaf(p, b.y, acc[5]);
    acc[6] = fmaf(p, b.z, acc[6]); acc[7] = fmaf(p, b.w, acc[7]);
}

__device__ __forceinline__ void qload(const float* src, float* qs) {
    float4 a = *(const float4*)(src);
    float4 b = *(const float4*)(src + 4);
    qs[0] = a.x * SCL; qs[1] = a.y * SCL; qs[2] = a.z * SCL; qs[3] = a.w * SCL;
    qs[4] = b.x * SCL; qs[5] = b.y * SCL; qs[6] = b.z * SCL; qs[7] = b.w * SCL;
}

__global__ __launch_bounds__(128) void attn_kernel(
    const float* __restrict__ q, const float* __restrict__ k,
    const float* __restrict__ v, const unsigned int* __restrict__ packedT,
    float* __restrict__ ao)
{
    __shared__ float kv[352 * 16];   // 22.5 KB: [m][k0..7, v0..7], zero-pad
    const int tid = threadIdx.x;
    const int h = blockIdx.x, bt = blockIdx.y;
    const int base = (bt * NN) * 64 + h * 8;

    #pragma unroll 2
    for (int qd = tid; qd < 352 * 4; qd += 128) {
        int m = qd >> 2, part = qd & 3;
        float4 val = make_float4(0.f, 0.f, 0.f, 0.f);
        if (m < NN) {
            const float* src = (part < 2) ? (k + base + m * 64 + part * 4)
                                          : (v + base + m * 64 + (part - 2) * 4);
            val = *(const float4*)src;
        }
        *(float4*)&kv[m * 16 + part * 4] = val;
    }
    __syncthreads();

    const int  n0 = tid;            // 0..127, always active
    const int  n1 = tid + 128;      // 128..255, always active
    const bool a2 = (tid + 256 < NN);
    const int  n2 = a2 ? tid + 256 : 0;

    float q0[8], q1[8], q2[8];
    qload(q + base + n0 * 64, q0);
    qload(q + base + n1 * 64, q1);
    qload(q + base + n2 * 64, q2);

    float acc0[8] = {0,0,0,0,0,0,0,0};
    float acc1[8] = {0,0,0,0,0,0,0,0};
    float acc2[8] = {0,0,0,0,0,0,0,0};
    float sum0 = 0.f, sum1 = 0.f, sum2 = 0.f;

    unsigned int mw0 = packedT[n0];
    unsigned int mw1 = packedT[n1];
    unsigned int mw2 = packedT[n2];
    for (int w = 0; w < 11; ++w) {
        unsigned int nx0 = 0u, nx1 = 0u, nx2 = 0u;
        if (w < 10) {
            nx0 = packedT[(w + 1) * NN + n0];
            nx1 = packedT[(w + 1) * NN + n1];
            nx2 = packedT[(w + 1) * NN + n2];
        }
        const float* kvw = kv + w * 512;
        #pragma unroll
        for (int b = 0; b < 32; ++b) {
            float4 ka  = *(const float4*)(kvw + b * 16);
            float4 kb4 = *(const float4*)(kvw + b * 16 + 4);
            float4 va  = *(const float4*)(kvw + b * 16 + 8);
            float4 vb4 = *(const float4*)(kvw + b * 16 + 12);

            float e0 = __builtin_amdgcn_exp2f(dot8(q0, ka, kb4));
            float p0 = (mw0 & (1u << b)) ? e0 : 0.f;
            sum0 += p0; pv8(acc0, p0, va, vb4);

            float e1 = __builtin_amdgcn_exp2f(dot8(q1, ka, kb4));
            float p1 = (mw1 & (1u << b)) ? e1 : 0.f;
            sum1 += p1; pv8(acc1, p1, va, vb4);

            float e2 = __builtin_amdgcn_exp2f(dot8(q2, ka, kb4));
            float p2 = (mw2 & (1u << b)) ? e2 : 0.f;
            sum2 += p2; pv8(acc2, p2, va, vb4);
        }
        mw0 = nx0; mw1 = nx1; mw2 = nx2;
    }

    {
        float inv = 1.0f / sum0;
        float4 o0 = {acc0[0]*inv, acc0[1]*inv, acc0[2]*inv, acc0[3]*inv};
        float4 o1 = {acc0[4]*inv, acc0[5]*inv, acc0[6]*inv, acc0[7]*inv};
        *(float4*)(ao + base + n0 * 64)     = o0;
        *(float4*)(ao + base + n0 * 64 + 4) = o1;
    }
    {
        float inv = 1.0f / sum1;
        float4 o0 = {acc1[0]*inv, acc1[1]*inv, acc1[2]*inv, acc1[3]*inv};
        float4 o1 = {acc1[4]*inv, acc1[5]*inv, acc1[6]*inv, acc1[7]*inv};
        *(float4*)(ao + base + n1 * 64)     = o0;
        *(float4*)(ao + base + n1 * 64 + 4) = o1;
    }
    if (a2) {
        float inv = 1.0f / sum2;
        float4 o0 = {acc2[0]*inv, acc2[1]*inv, acc2[2]*inv, acc2[3]*inv};
        float4 o1 = {acc2[4]*inv, acc2[5]*inv, acc2[6]*inv, acc2[7]*inv};
        *(float4*)(ao + base + n2 * 64)     = o0;
        *(float4*)(ao + base + n2 * 64 + 4) = o1;
    }
}

// ---------------------------------------------------------------------------
// Kernel 3: out = gelu(ao @ W10.T + b10) @ W11.T + b11.  64-row tiles,
// 128 threads, thread = 8 rows x 4 cols (32 FMA per 3 b128 reads).
// ---------------------------------------------------------------------------
__global__ __launch_bounds__(128) void proj_kernel(
    const float* __restrict__ ao,
    const float* __restrict__ W10, const float* __restrict__ b10,
    const float* __restrict__ W11, const float* __restrict__ b11,
    float* __restrict__ out)
{
    __shared__ float W10s[64 * 68];   // [i][c]
    __shared__ float W11s[64 * 68];
    __shared__ float aT[64 * 68];     // [i][r]
    __shared__ float hT[64 * 68];     // [c][r]
    const int tid  = threadIdx.x;
    const int row0 = blockIdx.x * 64;

    #pragma unroll 4
    for (int idx = tid; idx < 4096; idx += 128) {
        int c = idx >> 6, i = idx & 63;
        W10s[i * 68 + c] = W10[idx];
        W11s[i * 68 + c] = W11[idx];
    }
    #pragma unroll 4
    for (int idx = tid; idx < 4096; idx += 128) {
        int r = idx >> 6, i = idx & 63;
        int R = row0 + r;
        aT[i * 68 + r] = (R < NROWS) ? ao[R * 64 + i] : 0.f;
    }
    __syncthreads();

    const int cg4 = (tid & 15) * 4;
    const int rg8 = (tid >> 4) * 8;

    float acc[8][4];
    {
        const float4 bias = *(const float4*)(b10 + cg4);
        #pragma unroll
        for (int rr = 0; rr < 8; ++rr) {
            acc[rr][0] = bias.x; acc[rr][1] = bias.y;
            acc[rr][2] = bias.z; acc[rr][3] = bias.w;
        }
    }
    #pragma unroll 4
    for (int i = 0; i < 64; ++i) {
        float4 w  = *(const float4*)&W10s[i * 68 + cg4];
        float4 x0 = *(const float4*)&aT[i * 68 + rg8];
        float4 x1 = *(const float4*)&aT[i * 68 + rg8 + 4];
        const float xr[8] = {x0.x, x0.y, x0.z, x0.w, x1.x, x1.y, x1.z, x1.w};
        #pragma unroll
        for (int rr = 0; rr < 8; ++rr) {
            acc[rr][0] = fmaf(xr[rr], w.x, acc[rr][0]);
            acc[rr][1] = fmaf(xr[rr], w.y, acc[rr][1]);
            acc[rr][2] = fmaf(xr[rr], w.z, acc[rr][2]);
            acc[rr][3] = fmaf(xr[rr], w.w, acc[rr][3]);
        }
    }
    // h -> hT[c][r] (gelu applied), b128 over 4 consecutive rows
    #pragma unroll
    for (int cc = 0; cc < 4; ++cc) {
        float4 g0 = {gelu_f(acc[0][cc]), gelu_f(acc[1][cc]),
                     gelu_f(acc[2][cc]), gelu_f(acc[3][cc])};
        float4 g1 = {gelu_f(acc[4][cc]), gelu_f(acc[5][cc]),
                     gelu_f(acc[6][cc]), gelu_f(acc[7][cc])};
        *(float4*)&hT[(cg4 + cc) * 68 + rg8]     = g0;
        *(float4*)&hT[(cg4 + cc) * 68 + rg8 + 4] = g1;
    }
    __syncthreads();

    {
        const float4 bias = *(const float4*)(b11 + cg4);
        #pragma unroll
        for (int rr = 0; rr < 8; ++rr) {
            acc[rr][0] = bias.x; acc[rr][1] = bias.y;
            acc[rr][2] = bias.z; acc[rr][3] = bias.w;
        }
    }
    #pragma unroll 4
    for (int i = 0; i < 64; ++i) {
        float4 w  = *(const float4*)&W11s[i * 68 + cg4];
        float4 x0 = *(const float4*)&hT[i * 68 + rg8];
        float4 x1 = *(const float4*)&hT[i * 68 + rg8 + 4];
        const float xr[8] = {x0.x, x0.y, x0.z, x0.w, x1.x, x1.y, x1.z, x1.w};
        #pragma unroll
        for (int rr = 0; rr < 8; ++rr) {
            acc[rr][0] = fmaf(xr[rr], w.x, acc[rr][0]);
            acc[rr][1] = fmaf(xr[rr], w.y, acc[rr][1]);
            acc[rr][2] = fmaf(xr[rr], w.z, acc[rr][2]);
            acc[rr][3] = fmaf(xr[rr], w.w, acc[rr][3]);
        }
    }
    #pragma unroll
    for (int rr = 0; rr < 8; ++rr) {
        int R = row0 + rg8 + rr;
        if (R < NROWS) {
            float4 o = {acc[rr][0], acc[rr][1], acc[rr][2], acc[rr][3]};
            *(float4*)&out[R * 64 + cg4] = o;
        }
    }
}

extern "C" void kernel_launch(void* const* d_in, const int* in_sizes, int n_in,
                              void* d_out, int out_size, void* d_ws, size_t ws_size,
                              hipStream_t stream) {
    const float* X   = (const float*)d_in[0];
    const float* STE = (const float*)d_in[1];
    const int*   adj = (const int*)d_in[2];
    const float* W7  = (const float*)d_in[3];
    const float* b7  = (const float*)d_in[4];
    const float* W8  = (const float*)d_in[5];
    const float* b8  = (const float*)d_in[6];
    const float* W9  = (const float*)d_in[7];
    const float* b9  = (const float*)d_in[8];
    const float* W10 = (const float*)d_in[9];
    const float* b10 = (const float*)d_in[10];
    const float* W11 = (const float*)d_in[11];
    const float* b11 = (const float*)d_in[12];

    float* ws = (float*)d_ws;
    const long S = (long)NROWS * 64;  // 1,996,800 floats
    float* qb = ws;
    float* kb = ws + S;
    float* vb = ws + 2 * S;
    float* ab = ws + 3 * S;
    unsigned int* pk = (unsigned int*)(ws + 4 * S);  // 11*NN words

    pack_adj_kernel<<<(11 * NN + 255) / 256, 256, 0, stream>>>(adj, pk);
    qkv_kernel<<<dim3(488), 128, 0, stream>>>(X, STE, W7, b7, W8, b8, W9, b9,
                                              qb, kb, vb);
    attn_kernel<<<dim3(8, BT), 128, 0, stream>>>(qb, kb, vb, pk, ab);
    proj_kernel<<<dim3(488), 128, 0, stream>>>(ab, W10, b10, W11, b11,
                                               (float*)d_out);
}

// Round 6
// 219.375 us; speedup vs baseline: 1.2980x; 1.2980x over previous
//
#include <hip/hip_runtime.h>
#include <math.h>

#define NN 325
#define BT 96
// fold softmax scale and log2(e) into q: exp(s/sqrt8) == exp2(s * SCL)
#define SCL (0.35355339059327373f * 1.4426950408889634f)

typedef _Float16 half_t;
typedef half_t half4_t __attribute__((ext_vector_type(4)));
typedef half_t half2_t __attribute__((ext_vector_type(2)));
typedef float float4_t __attribute__((ext_vector_type(4)));

__device__ __forceinline__ float gelu_f(float x) {
    return 0.5f * x * (1.0f + erff(x * 0.70710678118654752f));
}

// ---------------------------------------------------------------------------
// Kernel 0: pack adj into transposed bitmasks: packedT[w*NN + n] holds bits
// for columns m = 32w..32w+31 of row n. Bits for m >= NN are 0.
// ---------------------------------------------------------------------------
__global__ void pack_adj_kernel(const int* __restrict__ adj,
                                unsigned int* __restrict__ packedT)
{
    int idx = blockIdx.x * 256 + threadIdx.x;
    if (idx >= 11 * NN) return;
    int w = idx / NN, n = idx - w * NN;
    unsigned int bits = 0u;
    #pragma unroll 8
    for (int j = 0; j < 32; ++j) {
        int m = w * 32 + j;
        if (m < NN && adj[n * NN + m] > 0) bits |= (1u << j);
    }
    packedT[w * NN + n] = bits;
}

// ---------------------------------------------------------------------------
// Kernel 1: q/k/v = gelu(concat(X,STE) @ W.T + b).  R2 version (known-good).
// ---------------------------------------------------------------------------
__device__ __forceinline__ void qkv_phase(
    const float* __restrict__ W, const float* __restrict__ b,
    float* __restrict__ outp, const float* xs, float* ws,
    int tid, int bt, int r0)
{
    __syncthreads();
    for (int idx = tid; idx < 64 * 128; idx += 256) {
        int c = idx >> 7, i = idx & 127;
        ws[i * 68 + c] = W[idx];   // transposed store
    }
    __syncthreads();

    const int c4 = (tid & 15) * 4;
    const int rg = tid >> 4;

    float4 bias = *(const float4*)(b + c4);
    float4 acc0 = bias, acc1 = bias;
    const float* x0p = xs + rg * 132;
    const float* x1p = xs + (rg + 16) * 132;
    #pragma unroll 4
    for (int i = 0; i < 128; ++i) {
        float xa = x0p[i], xb = x1p[i];
        float4 w4 = *(const float4*)&ws[i * 68 + c4];
        acc0.x = fmaf(xa, w4.x, acc0.x);
        acc0.y = fmaf(xa, w4.y, acc0.y);
        acc0.z = fmaf(xa, w4.z, acc0.z);
        acc0.w = fmaf(xa, w4.w, acc0.w);
        acc1.x = fmaf(xb, w4.x, acc1.x);
        acc1.y = fmaf(xb, w4.y, acc1.y);
        acc1.z = fmaf(xb, w4.z, acc1.z);
        acc1.w = fmaf(xb, w4.w, acc1.w);
    }
    int n0 = r0 + rg, n1 = r0 + rg + 16;
    if (n0 < NN) {
        float4 g;
        g.x = gelu_f(acc0.x); g.y = gelu_f(acc0.y);
        g.z = gelu_f(acc0.z); g.w = gelu_f(acc0.w);
        *(float4*)&outp[(bt * NN + n0) * 64 + c4] = g;
    }
    if (n1 < NN) {
        float4 g;
        g.x = gelu_f(acc1.x); g.y = gelu_f(acc1.y);
        g.z = gelu_f(acc1.z); g.w = gelu_f(acc1.w);
        *(float4*)&outp[(bt * NN + n1) * 64 + c4] = g;
    }
}

__global__ __launch_bounds__(256) void qkv_kernel(
    const float* __restrict__ X, const float* __restrict__ STE,
    const float* __restrict__ W7, const float* __restrict__ b7,
    const float* __restrict__ W8, const float* __restrict__ b8,
    const float* __restrict__ W9, const float* __restrict__ b9,
    float* __restrict__ q, float* __restrict__ k, float* __restrict__ v)
{
    __shared__ float xs[32 * 132];
    __shared__ float ws[128 * 68];
    const int tid = threadIdx.x;
    const int bt  = blockIdx.y;
    const int r0  = blockIdx.x * 32;

    for (int idx = tid; idx < 32 * 128; idx += 256) {
        int r = idx >> 7, i = idx & 127;
        int n = r0 + r;
        float val = 0.0f;
        if (n < NN) {
            val = (i < 64) ? X[(bt * NN + n) * 64 + i]
                           : STE[(bt * NN + n) * 64 + (i - 64)];
        }
        xs[r * 132 + i] = val;
    }

    qkv_phase(W7, b7, q, xs, ws, tid, bt, r0);
    qkv_phase(W8, b8, k, xs, ws, tid, bt, r0);
    qkv_phase(W9, b9, v, xs, ws, tid, bt, r0);
}

// ---------------------------------------------------------------------------
// Kernel 2: MFMA flash attention.  One 256-thr block per (bt,h).
// S^T = K·Q^T via mfma_f32_16x16x16f16: D[row=m-local][col=n-local] means
// lane holds P[n = n0+(lane&15)][m = m0+quad*4+r] — exactly the B-operand
// layout for O^T = V^T·P^T.  Two passes (row-max, then exp2+PV).  Row state
// (max, sum) is per-lane + 2 shfl_xor across quads.  f16 fragments in LDS
// with 10-dword row strides (2-way bank alias = free).
// ---------------------------------------------------------------------------
__global__ __launch_bounds__(256) void attn_kernel(
    const float* __restrict__ q, const float* __restrict__ k,
    const float* __restrict__ v, const unsigned int* __restrict__ packedT,
    float* __restrict__ ao)
{
    __shared__ __attribute__((aligned(16))) half_t Q16[336 * 20]; // [n][d0..15]
    __shared__ __attribute__((aligned(16))) half_t K16[336 * 20]; // [m][d0..15]
    __shared__ __attribute__((aligned(16))) half_t VT16[16 * 340];// [c][m]
    __shared__ unsigned int Ms[11 * 336];
    const int tid = threadIdx.x;
    const int h = blockIdx.x, bt = blockIdx.y;
    const int base = (bt * NN) * 64 + h * 8;

    // zero VT16 (rows 8..15 stay zero; cols >= NN stay zero)
    for (int idx = tid; idx < 16 * 340 / 2; idx += 256)
        ((half2_t*)VT16)[idx] = (half2_t)(half_t)0.f;

    // stage Q (scaled) and K rows; rows >= NN and d >= 8 are zero
    for (int r = tid; r < 336; r += 256) {
        float4 qa = {0,0,0,0}, qb4 = {0,0,0,0};
        float4 ka = {0,0,0,0}, kb4 = {0,0,0,0};
        if (r < NN) {
            qa  = *(const float4*)(q + base + r * 64);
            qb4 = *(const float4*)(q + base + r * 64 + 4);
            ka  = *(const float4*)(k + base + r * 64);
            kb4 = *(const float4*)(k + base + r * 64 + 4);
        }
        half2_t* qrow = (half2_t*)&Q16[r * 20];
        half2_t* krow = (half2_t*)&K16[r * 20];
        half2_t t;
        t[0] = (half_t)(qa.x * SCL); t[1] = (half_t)(qa.y * SCL); qrow[0] = t;
        t[0] = (half_t)(qa.z * SCL); t[1] = (half_t)(qa.w * SCL); qrow[1] = t;
        t[0] = (half_t)(qb4.x * SCL); t[1] = (half_t)(qb4.y * SCL); qrow[2] = t;
        t[0] = (half_t)(qb4.z * SCL); t[1] = (half_t)(qb4.w * SCL); qrow[3] = t;
        t[0] = (half_t)0.f; t[1] = (half_t)0.f;
        qrow[4] = t; qrow[5] = t; qrow[6] = t; qrow[7] = t;
        half2_t u;
        u[0] = (half_t)ka.x; u[1] = (half_t)ka.y; krow[0] = u;
        u[0] = (half_t)ka.z; u[1] = (half_t)ka.w; krow[1] = u;
        u[0] = (half_t)kb4.x; u[1] = (half_t)kb4.y; krow[2] = u;
        u[0] = (half_t)kb4.z; u[1] = (half_t)kb4.w; krow[3] = u;
        u[0] = (half_t)0.f; u[1] = (half_t)0.f;
        krow[4] = u; krow[5] = u; krow[6] = u; krow[7] = u;
    }

    // stage mask words, n padded to 336 with 0
    for (int idx = tid; idx < 11 * 336; idx += 256) {
        int w = idx / 336, n = idx - w * 336;
        Ms[idx] = (n < NN) ? packedT[w * NN + n] : 0u;
    }
    __syncthreads();

    // scatter V into VT16[c][m] (rows 0..7)
    for (int m = tid; m < NN; m += 256) {
        float4 va  = *(const float4*)(v + base + m * 64);
        float4 vb4 = *(const float4*)(v + base + m * 64 + 4);
        VT16[0 * 340 + m] = (half_t)va.x;
        VT16[1 * 340 + m] = (half_t)va.y;
        VT16[2 * 340 + m] = (half_t)va.z;
        VT16[3 * 340 + m] = (half_t)va.w;
        VT16[4 * 340 + m] = (half_t)vb4.x;
        VT16[5 * 340 + m] = (half_t)vb4.y;
        VT16[6 * 340 + m] = (half_t)vb4.z;
        VT16[7 * 340 + m] = (half_t)vb4.w;
    }
    __syncthreads();

    const int lane = tid & 63;
    const int wv   = tid >> 6;      // wave 0..3
    const int l15  = lane & 15;
    const int quad = lane >> 4;
    const int qsh  = quad * 4;

    for (int t = wv; t < 21; t += 4) {
        const int n0 = t * 16;
        const int n  = n0 + l15;
        const half4_t qf = *(const half4_t*)&Q16[n * 20 + qsh];

        // pass A: row max (per-lane over its 4 m-columns per tile)
        float rm = -3.0e38f;
        for (int mt = 0; mt < 21; ++mt) {
            half4_t kf = *(const half4_t*)&K16[(mt * 16 + l15) * 20 + qsh];
            float4_t s = __builtin_amdgcn_mfma_f32_16x16x16f16(
                kf, qf, (float4_t){0.f, 0.f, 0.f, 0.f}, 0, 0, 0);
            unsigned int bits = Ms[(mt >> 1) * 336 + n];
            unsigned int sh = bits >> (((mt & 1) << 4) + qsh);
            rm = fmaxf(rm, (sh & 1u) ? s[0] : -3.0e38f);
            rm = fmaxf(rm, (sh & 2u) ? s[1] : -3.0e38f);
            rm = fmaxf(rm, (sh & 4u) ? s[2] : -3.0e38f);
            rm = fmaxf(rm, (sh & 8u) ? s[3] : -3.0e38f);
        }
        rm = fmaxf(rm, __shfl_xor(rm, 16, 64));
        rm = fmaxf(rm, __shfl_xor(rm, 32, 64));

        // pass B: p = exp2(s - rm), f16 P straight into PV MFMA
        float4_t acc = {0.f, 0.f, 0.f, 0.f};
        float sum = 0.f;
        for (int mt = 0; mt < 21; ++mt) {
            half4_t kf = *(const half4_t*)&K16[(mt * 16 + l15) * 20 + qsh];
            float4_t s = __builtin_amdgcn_mfma_f32_16x16x16f16(
                kf, qf, (float4_t){0.f, 0.f, 0.f, 0.f}, 0, 0, 0);
            unsigned int bits = Ms[(mt >> 1) * 336 + n];
            unsigned int sh = bits >> (((mt & 1) << 4) + qsh);
            float p0 = (sh & 1u) ? __builtin_amdgcn_exp2f(s[0] - rm) : 0.f;
            float p1 = (sh & 2u) ? __builtin_amdgcn_exp2f(s[1] - rm) : 0.f;
            float p2 = (sh & 4u) ? __builtin_amdgcn_exp2f(s[2] - rm) : 0.f;
            float p3 = (sh & 8u) ? __builtin_amdgcn_exp2f(s[3] - rm) : 0.f;
            sum += (p0 + p1) + (p2 + p3);
            half4_t pf;
            pf[0] = (half_t)p0; pf[1] = (half_t)p1;
            pf[2] = (half_t)p2; pf[3] = (half_t)p3;
            half4_t vf = *(const half4_t*)&VT16[l15 * 340 + mt * 16 + qsh];
            acc = __builtin_amdgcn_mfma_f32_16x16x16f16(vf, pf, acc, 0, 0, 0);
        }
        sum += __shfl_xor(sum, 16, 64);
        sum += __shfl_xor(sum, 32, 64);

        if (quad < 2 && n < NN) {
            float inv = 1.0f / sum;
            float4 o;
            o.x = acc[0] * inv; o.y = acc[1] * inv;
            o.z = acc[2] * inv; o.w = acc[3] * inv;
            *(float4*)(ao + base + n * 64 + qsh) = o;
        }
    }
}

// ---------------------------------------------------------------------------
// Kernel 3: out = gelu(ao @ W10.T + b10) @ W11.T + b11.  R2 version
// (16 rows/block, grid 1950 — known-good).
// ---------------------------------------------------------------------------
__global__ __launch_bounds__(256) void proj_kernel(
    const float* __restrict__ ao,
    const float* __restrict__ W10, const float* __restrict__ b10,
    const float* __restrict__ W11, const float* __restrict__ b11,
    float* __restrict__ out)
{
    __shared__ float W10s[64 * 65];
    __shared__ float W11s[64 * 65];
    __shared__ float as_[16 * 64];
    __shared__ float hs[16 * 64];
    const int tid = threadIdx.x;
    const int rowbase = blockIdx.x * 16;

    for (int idx = tid; idx < 4096; idx += 256) {
        int c = idx >> 6, i = idx & 63;
        W10s[i * 65 + c] = W10[idx];
        W11s[i * 65 + c] = W11[idx];
    }
    for (int idx = tid; idx < 1024; idx += 256)
        as_[idx] = ao[rowbase * 64 + idx];
    __syncthreads();

    const int c = tid & 63, rg = tid >> 6;
    float bb = b10[c];
    float acc[4];
    #pragma unroll
    for (int rr = 0; rr < 4; ++rr) acc[rr] = bb;
    #pragma unroll 8
    for (int i = 0; i < 64; ++i) {
        float w = W10s[i * 65 + c];
        #pragma unroll
        for (int rr = 0; rr < 4; ++rr)
            acc[rr] = fmaf(as_[(rg * 4 + rr) * 64 + i], w, acc[rr]);
    }
    #pragma unroll
    for (int rr = 0; rr < 4; ++rr)
        hs[(rg * 4 + rr) * 64 + c] = gelu_f(acc[rr]);
    __syncthreads();

    float bb2 = b11[c];
    float acc2[4];
    #pragma unroll
    for (int rr = 0; rr < 4; ++rr) acc2[rr] = bb2;
    #pragma unroll 8
    for (int i = 0; i < 64; ++i) {
        float w = W11s[i * 65 + c];
        #pragma unroll
        for (int rr = 0; rr < 4; ++rr)
            acc2[rr] = fmaf(hs[(rg * 4 + rr) * 64 + i], w, acc2[rr]);
    }
    #pragma unroll
    for (int rr = 0; rr < 4; ++rr)
        out[(rowbase + rg * 4 + rr) * 64 + c] = acc2[rr];
}

extern "C" void kernel_launch(void* const* d_in, const int* in_sizes, int n_in,
                              void* d_out, int out_size, void* d_ws, size_t ws_size,
                              hipStream_t stream) {
    const float* X   = (const float*)d_in[0];
    const float* STE = (const float*)d_in[1];
    const int*   adj = (const int*)d_in[2];
    const float* W7  = (const float*)d_in[3];
    const float* b7  = (const float*)d_in[4];
    const float* W8  = (const float*)d_in[5];
    const float* b8  = (const float*)d_in[6];
    const float* W9  = (const float*)d_in[7];
    const float* b9  = (const float*)d_in[8];
    const float* W10 = (const float*)d_in[9];
    const float* b10 = (const float*)d_in[10];
    const float* W11 = (const float*)d_in[11];
    const float* b11 = (const float*)d_in[12];

    float* ws = (float*)d_ws;
    const long S = (long)BT * NN * 64;  // 1,996,800 floats
    float* qb = ws;
    float* kb = ws + S;
    float* vb = ws + 2 * S;
    float* ab = ws + 3 * S;
    unsigned int* pk = (unsigned int*)(ws + 4 * S);  // 11*NN words

    pack_adj_kernel<<<(11 * NN + 255) / 256, 256, 0, stream>>>(adj, pk);
    qkv_kernel<<<dim3(11, BT), 256, 0, stream>>>(X, STE, W7, b7, W8, b8, W9, b9,
                                                 qb, kb, vb);
    attn_kernel<<<dim3(8, BT), 256, 0, stream>>>(qb, kb, vb, pk, ab);
    proj_kernel<<<dim3(1950), 256, 0, stream>>>(ab, W10, b10, W11, b11,
                                                (float*)d_out);
}

// Round 7
// 175.858 us; speedup vs baseline: 1.6192x; 1.2475x over previous
//
#include <hip/hip_runtime.h>
#include <math.h>

#define NN 325
#define BT 96
#define NROWS (BT * NN)   // 31200
// fold softmax scale and log2(e) into q: exp(s/sqrt8) == exp2(s * SCL)
#define SCL (0.35355339059327373f * 1.4426950408889634f)

typedef _Float16 half_t;
typedef half_t half4_t __attribute__((ext_vector_type(4)));
typedef half_t half2_t __attribute__((ext_vector_type(2)));
typedef float float4_t __attribute__((ext_vector_type(4)));

__device__ __forceinline__ float gelu_f(float x) {
    return 0.5f * x * (1.0f + erff(x * 0.70710678118654752f));
}

// ---------------------------------------------------------------------------
// Kernel 0: pack adj into transposed bitmasks: packedT[w*NN + n] holds bits
// for columns m = 32w..32w+31 of row n. Bits for m >= NN are 0.
// ---------------------------------------------------------------------------
__global__ void pack_adj_kernel(const int* __restrict__ adj,
                                unsigned int* __restrict__ packedT)
{
    int idx = blockIdx.x * 256 + threadIdx.x;
    if (idx >= 11 * NN) return;
    int w = idx / NN, n = idx - w * NN;
    unsigned int bits = 0u;
    #pragma unroll 8
    for (int j = 0; j < 32; ++j) {
        int m = w * 32 + j;
        if (m < NN && adj[n * NN + m] > 0) bits |= (1u << j);
    }
    packedT[w * NN + n] = bits;
}

// ---------------------------------------------------------------------------
// Kernel 1: q/k/v = gelu(concat(X,STE) @ W.T + b) via f16 MFMA.
// 64 rows/block, 256 thr (4 waves), wave = 16-row tile x 64 cols.
// A = x16[m][k] (native row layout), B[k][c] = W[c][k] = w16 native row
// layout — NO transposed staging (kills R6's 2.4M bank conflicts).
// D[row=quad*4+reg][col=l15] -> gelu -> f32 global store.
// ---------------------------------------------------------------------------
#define XS 136   // half stride per 128-k row (68 dwords)

__device__ __forceinline__ void qkv_mfma_phase(
    const half_t* x16, const half_t* w16p, const float* __restrict__ b,
    float* __restrict__ outp, int row0, int rbase, int l15, int quad)
{
    float4_t acc[4];
    #pragma unroll
    for (int ct = 0; ct < 4; ++ct) {
        float bias = b[ct * 16 + l15];
        acc[ct] = (float4_t){bias, bias, bias, bias};
    }
    #pragma unroll
    for (int kk = 0; kk < 8; ++kk) {
        half4_t a = *(const half4_t*)&x16[(rbase + l15) * XS + kk * 16 + quad * 4];
        #pragma unroll
        for (int ct = 0; ct < 4; ++ct) {
            half4_t bf = *(const half4_t*)&w16p[(ct * 16 + l15) * XS + kk * 16 + quad * 4];
            acc[ct] = __builtin_amdgcn_mfma_f32_16x16x16f16(a, bf, acc[ct], 0, 0, 0);
        }
    }
    #pragma unroll
    for (int ct = 0; ct < 4; ++ct) {
        #pragma unroll
        for (int rr = 0; rr < 4; ++rr) {
            int R = row0 + rbase + quad * 4 + rr;
            if (R < NROWS)
                outp[R * 64 + ct * 16 + l15] = gelu_f(acc[ct][rr]);
        }
    }
}

__global__ __launch_bounds__(256) void qkv_kernel(
    const float* __restrict__ X, const float* __restrict__ STE,
    const float* __restrict__ W7, const float* __restrict__ b7,
    const float* __restrict__ W8, const float* __restrict__ b8,
    const float* __restrict__ W9, const float* __restrict__ b9,
    float* __restrict__ q, float* __restrict__ k, float* __restrict__ v)
{
    __shared__ __attribute__((aligned(16))) half_t x16[64 * XS];
    __shared__ __attribute__((aligned(16))) half_t w16[3][64 * XS];
    const int tid  = threadIdx.x;
    const int row0 = blockIdx.x * 64;

    // stage x = concat(X, STE) -> f16, zero-fill OOB rows
    #pragma unroll 2
    for (int idx = tid; idx < 64 * 32; idx += 256) {
        int r = idx >> 5, c4 = idx & 31;
        int R = row0 + r;
        float4 f = {0.f, 0.f, 0.f, 0.f};
        if (R < NROWS)
            f = (c4 < 16) ? *(const float4*)(X + R * 64 + c4 * 4)
                          : *(const float4*)(STE + R * 64 + (c4 - 16) * 4);
        half4_t hv;
        hv[0] = (half_t)f.x; hv[1] = (half_t)f.y;
        hv[2] = (half_t)f.z; hv[3] = (half_t)f.w;
        *(half4_t*)&x16[r * XS + c4 * 4] = hv;
    }
    // stage all three weight matrices (native [c][k] layout)
    #pragma unroll 2
    for (int idx = tid; idx < 3 * 64 * 32; idx += 256) {
        int p = idx >> 11, rem = idx & 2047;
        int c = rem >> 5, c4 = rem & 31;
        const float* Wp = (p == 0) ? W7 : (p == 1) ? W8 : W9;
        float4 f = *(const float4*)(Wp + c * 128 + c4 * 4);
        half4_t hv;
        hv[0] = (half_t)f.x; hv[1] = (half_t)f.y;
        hv[2] = (half_t)f.z; hv[3] = (half_t)f.w;
        *(half4_t*)&w16[p][c * XS + c4 * 4] = hv;
    }
    __syncthreads();

    const int lane = tid & 63, wv = tid >> 6;
    const int l15 = lane & 15, quad = lane >> 4;
    const int rbase = wv * 16;

    qkv_mfma_phase(x16, w16[0], b7, q, row0, rbase, l15, quad);
    qkv_mfma_phase(x16, w16[1], b8, k, row0, rbase, l15, quad);
    qkv_mfma_phase(x16, w16[2], b9, v, row0, rbase, l15, quad);
}

// ---------------------------------------------------------------------------
// Kernel 2: MFMA flash attention (R6 version — unchanged, validated).
// ---------------------------------------------------------------------------
__global__ __launch_bounds__(256) void attn_kernel(
    const float* __restrict__ q, const float* __restrict__ k,
    const float* __restrict__ v, const unsigned int* __restrict__ packedT,
    float* __restrict__ ao)
{
    __shared__ __attribute__((aligned(16))) half_t Q16[336 * 20]; // [n][d0..15]
    __shared__ __attribute__((aligned(16))) half_t K16[336 * 20]; // [m][d0..15]
    __shared__ __attribute__((aligned(16))) half_t VT16[16 * 340];// [c][m]
    __shared__ unsigned int Ms[11 * 336];
    const int tid = threadIdx.x;
    const int h = blockIdx.x, bt = blockIdx.y;
    const int base = (bt * NN) * 64 + h * 8;

    for (int idx = tid; idx < 16 * 340 / 2; idx += 256)
        ((half2_t*)VT16)[idx] = (half2_t)(half_t)0.f;

    for (int r = tid; r < 336; r += 256) {
        float4 qa = {0,0,0,0}, qb4 = {0,0,0,0};
        float4 ka = {0,0,0,0}, kb4 = {0,0,0,0};
        if (r < NN) {
            qa  = *(const float4*)(q + base + r * 64);
            qb4 = *(const float4*)(q + base + r * 64 + 4);
            ka  = *(const float4*)(k + base + r * 64);
            kb4 = *(const float4*)(k + base + r * 64 + 4);
        }
        half2_t* qrow = (half2_t*)&Q16[r * 20];
        half2_t* krow = (half2_t*)&K16[r * 20];
        half2_t t;
        t[0] = (half_t)(qa.x * SCL); t[1] = (half_t)(qa.y * SCL); qrow[0] = t;
        t[0] = (half_t)(qa.z * SCL); t[1] = (half_t)(qa.w * SCL); qrow[1] = t;
        t[0] = (half_t)(qb4.x * SCL); t[1] = (half_t)(qb4.y * SCL); qrow[2] = t;
        t[0] = (half_t)(qb4.z * SCL); t[1] = (half_t)(qb4.w * SCL); qrow[3] = t;
        t[0] = (half_t)0.f; t[1] = (half_t)0.f;
        qrow[4] = t; qrow[5] = t; qrow[6] = t; qrow[7] = t;
        half2_t u;
        u[0] = (half_t)ka.x; u[1] = (half_t)ka.y; krow[0] = u;
        u[0] = (half_t)ka.z; u[1] = (half_t)ka.w; krow[1] = u;
        u[0] = (half_t)kb4.x; u[1] = (half_t)kb4.y; krow[2] = u;
        u[0] = (half_t)kb4.z; u[1] = (half_t)kb4.w; krow[3] = u;
        u[0] = (half_t)0.f; u[1] = (half_t)0.f;
        krow[4] = u; krow[5] = u; krow[6] = u; krow[7] = u;
    }

    for (int idx = tid; idx < 11 * 336; idx += 256) {
        int w = idx / 336, n = idx - w * 336;
        Ms[idx] = (n < NN) ? packedT[w * NN + n] : 0u;
    }
    __syncthreads();

    for (int m = tid; m < NN; m += 256) {
        float4 va  = *(const float4*)(v + base + m * 64);
        float4 vb4 = *(const float4*)(v + base + m * 64 + 4);
        VT16[0 * 340 + m] = (half_t)va.x;
        VT16[1 * 340 + m] = (half_t)va.y;
        VT16[2 * 340 + m] = (half_t)va.z;
        VT16[3 * 340 + m] = (half_t)va.w;
        VT16[4 * 340 + m] = (half_t)vb4.x;
        VT16[5 * 340 + m] = (half_t)vb4.y;
        VT16[6 * 340 + m] = (half_t)vb4.z;
        VT16[7 * 340 + m] = (half_t)vb4.w;
    }
    __syncthreads();

    const int lane = tid & 63;
    const int wv   = tid >> 6;
    const int l15  = lane & 15;
    const int quad = lane >> 4;
    const int qsh  = quad * 4;

    for (int t = wv; t < 21; t += 4) {
        const int n0 = t * 16;
        const int n  = n0 + l15;
        const half4_t qf = *(const half4_t*)&Q16[n * 20 + qsh];

        float rm = -3.0e38f;
        for (int mt = 0; mt < 21; ++mt) {
            half4_t kf = *(const half4_t*)&K16[(mt * 16 + l15) * 20 + qsh];
            float4_t s = __builtin_amdgcn_mfma_f32_16x16x16f16(
                kf, qf, (float4_t){0.f, 0.f, 0.f, 0.f}, 0, 0, 0);
            unsigned int bits = Ms[(mt >> 1) * 336 + n];
            unsigned int sh = bits >> (((mt & 1) << 4) + qsh);
            rm = fmaxf(rm, (sh & 1u) ? s[0] : -3.0e38f);
            rm = fmaxf(rm, (sh & 2u) ? s[1] : -3.0e38f);
            rm = fmaxf(rm, (sh & 4u) ? s[2] : -3.0e38f);
            rm = fmaxf(rm, (sh & 8u) ? s[3] : -3.0e38f);
        }
        rm = fmaxf(rm, __shfl_xor(rm, 16, 64));
        rm = fmaxf(rm, __shfl_xor(rm, 32, 64));

        float4_t acc = {0.f, 0.f, 0.f, 0.f};
        float sum = 0.f;
        for (int mt = 0; mt < 21; ++mt) {
            half4_t kf = *(const half4_t*)&K16[(mt * 16 + l15) * 20 + qsh];
            float4_t s = __builtin_amdgcn_mfma_f32_16x16x16f16(
                kf, qf, (float4_t){0.f, 0.f, 0.f, 0.f}, 0, 0, 0);
            unsigned int bits = Ms[(mt >> 1) * 336 + n];
            unsigned int sh = bits >> (((mt & 1) << 4) + qsh);
            float p0 = (sh & 1u) ? __builtin_amdgcn_exp2f(s[0] - rm) : 0.f;
            float p1 = (sh & 2u) ? __builtin_amdgcn_exp2f(s[1] - rm) : 0.f;
            float p2 = (sh & 4u) ? __builtin_amdgcn_exp2f(s[2] - rm) : 0.f;
            float p3 = (sh & 8u) ? __builtin_amdgcn_exp2f(s[3] - rm) : 0.f;
            sum += (p0 + p1) + (p2 + p3);
            half4_t pf;
            pf[0] = (half_t)p0; pf[1] = (half_t)p1;
            pf[2] = (half_t)p2; pf[3] = (half_t)p3;
            half4_t vf = *(const half4_t*)&VT16[l15 * 340 + mt * 16 + qsh];
            acc = __builtin_amdgcn_mfma_f32_16x16x16f16(vf, pf, acc, 0, 0, 0);
        }
        sum += __shfl_xor(sum, 16, 64);
        sum += __shfl_xor(sum, 32, 64);

        if (quad < 2 && n < NN) {
            float inv = 1.0f / sum;
            float4 o;
            o.x = acc[0] * inv; o.y = acc[1] * inv;
            o.z = acc[2] * inv; o.w = acc[3] * inv;
            *(float4*)(ao + base + n * 64 + qsh) = o;
        }
    }
}

// ---------------------------------------------------------------------------
// Kernel 3: out = gelu(ao @ W10.T + b10) @ W11.T + b11 via f16 MFMA.
// 64 rows/block, 256 thr; wave = 16-row tile; both stages fused, h in LDS
// (each wave writes/reads only its own row tile).
// ---------------------------------------------------------------------------
#define PS 72   // half stride per 64-k row (36 dwords)

__global__ __launch_bounds__(256) void proj_kernel(
    const float* __restrict__ ao,
    const float* __restrict__ W10, const float* __restrict__ b10,
    const float* __restrict__ W11, const float* __restrict__ b11,
    float* __restrict__ out)
{
    __shared__ __attribute__((aligned(16))) half_t a16[64 * PS];
    __shared__ __attribute__((aligned(16))) half_t wA[64 * PS];
    __shared__ __attribute__((aligned(16))) half_t wB[64 * PS];
    __shared__ __attribute__((aligned(16))) half_t h16[64 * PS];
    const int tid  = threadIdx.x;
    const int row0 = blockIdx.x * 64;

    for (int idx = tid; idx < 64 * 16; idx += 256) {
        int r = idx >> 4, c4 = idx & 15;
        int R = row0 + r;
        float4 f = {0.f, 0.f, 0.f, 0.f};
        if (R < NROWS) f = *(const float4*)(ao + R * 64 + c4 * 4);
        half4_t hv;
        hv[0] = (half_t)f.x; hv[1] = (half_t)f.y;
        hv[2] = (half_t)f.z; hv[3] = (half_t)f.w;
        *(half4_t*)&a16[r * PS + c4 * 4] = hv;

        float4 fA = *(const float4*)(W10 + r * 64 + c4 * 4);
        float4 fB = *(const float4*)(W11 + r * 64 + c4 * 4);
        half4_t hA, hB;
        hA[0] = (half_t)fA.x; hA[1] = (half_t)fA.y;
        hA[2] = (half_t)fA.z; hA[3] = (half_t)fA.w;
        hB[0] = (half_t)fB.x; hB[1] = (half_t)fB.y;
        hB[2] = (half_t)fB.z; hB[3] = (half_t)fB.w;
        *(half4_t*)&wA[r * PS + c4 * 4] = hA;
        *(half4_t*)&wB[r * PS + c4 * 4] = hB;
    }
    __syncthreads();

    const int lane = tid & 63, wv = tid >> 6;
    const int l15 = lane & 15, quad = lane >> 4;
    const int rbase = wv * 16;

    // stage 1: h = gelu(a @ W10.T + b10)
    float4_t acc[4];
    #pragma unroll
    for (int ct = 0; ct < 4; ++ct) {
        float bias = b10[ct * 16 + l15];
        acc[ct] = (float4_t){bias, bias, bias, bias};
    }
    #pragma unroll
    for (int kk = 0; kk < 4; ++kk) {
        half4_t a = *(const half4_t*)&a16[(rbase + l15) * PS + kk * 16 + quad * 4];
        #pragma unroll
        for (int ct = 0; ct < 4; ++ct) {
            half4_t bf = *(const half4_t*)&wA[(ct * 16 + l15) * PS + kk * 16 + quad * 4];
            acc[ct] = __builtin_amdgcn_mfma_f32_16x16x16f16(a, bf, acc[ct], 0, 0, 0);
        }
    }
    #pragma unroll
    for (int ct = 0; ct < 4; ++ct) {
        #pragma unroll
        for (int rr = 0; rr < 4; ++rr)
            h16[(rbase + quad * 4 + rr) * PS + ct * 16 + l15] =
                (half_t)gelu_f(acc[ct][rr]);
    }
    __syncthreads();

    // stage 2: out = h @ W11.T + b11
    #pragma unroll
    for (int ct = 0; ct < 4; ++ct) {
        float bias = b11[ct * 16 + l15];
        acc[ct] = (float4_t){bias, bias, bias, bias};
    }
    #pragma unroll
    for (int kk = 0; kk < 4; ++kk) {
        half4_t a = *(const half4_t*)&h16[(rbase + l15) * PS + kk * 16 + quad * 4];
        #pragma unroll
        for (int ct = 0; ct < 4; ++ct) {
            half4_t bf = *(const half4_t*)&wB[(ct * 16 + l15) * PS + kk * 16 + quad * 4];
            acc[ct] = __builtin_amdgcn_mfma_f32_16x16x16f16(a, bf, acc[ct], 0, 0, 0);
        }
    }
    #pragma unroll
    for (int ct = 0; ct < 4; ++ct) {
        #pragma unroll
        for (int rr = 0; rr < 4; ++rr) {
            int R = row0 + rbase + quad * 4 + rr;
            if (R < NROWS)
                out[R * 64 + ct * 16 + l15] = acc[ct][rr];
        }
    }
}

extern "C" void kernel_launch(void* const* d_in, const int* in_sizes, int n_in,
                              void* d_out, int out_size, void* d_ws, size_t ws_size,
                              hipStream_t stream) {
    const float* X   = (const float*)d_in[0];
    const float* STE = (const float*)d_in[1];
    const int*   adj = (const int*)d_in[2];
    const float* W7  = (const float*)d_in[3];
    const float* b7  = (const float*)d_in[4];
    const float* W8  = (const float*)d_in[5];
    const float* b8  = (const float*)d_in[6];
    const float* W9  = (const float*)d_in[7];
    const float* b9  = (const float*)d_in[8];
    const float* W10 = (const float*)d_in[9];
    const float* b10 = (const float*)d_in[10];
    const float* W11 = (const float*)d_in[11];
    const float* b11 = (const float*)d_in[12];

    float* ws = (float*)d_ws;
    const long S = (long)NROWS * 64;  // 1,996,800 floats
    float* qb = ws;
    float* kb = ws + S;
    float* vb = ws + 2 * S;
    float* ab = ws + 3 * S;
    unsigned int* pk = (unsigned int*)(ws + 4 * S);  // 11*NN words

    pack_adj_kernel<<<(11 * NN + 255) / 256, 256, 0, stream>>>(adj, pk);
    qkv_kernel<<<dim3((NROWS + 63) / 64), 256, 0, stream>>>(
        X, STE, W7, b7, W8, b8, W9, b9, qb, kb, vb);
    attn_kernel<<<dim3(8, BT), 256, 0, stream>>>(qb, kb, vb, pk, ab);
    proj_kernel<<<dim3((NROWS + 63) / 64), 256, 0, stream>>>(
        ab, W10, b10, W11, b11, (float*)d_out);
}

// Round 8
// 164.261 us; speedup vs baseline: 1.7335x; 1.0706x over previous
//
#include <hip/hip_runtime.h>
#include <math.h>

#define NN 325
#define BT 96
#define NROWS (BT * NN)   // 31200
// fold softmax scale and log2(e) into q: exp(s/sqrt8) == exp2(s * SCL)
#define SCL (0.35355339059327373f * 1.4426950408889634f)

typedef _Float16 half_t;
typedef half_t half4_t __attribute__((ext_vector_type(4)));
typedef half_t half2_t __attribute__((ext_vector_type(2)));
typedef float float4_t __attribute__((ext_vector_type(4)));

__device__ __forceinline__ float gelu_f(float x) {
    return 0.5f * x * (1.0f + erff(x * 0.70710678118654752f));
}

// ---------------------------------------------------------------------------
// Kernel 0: pack adj into transposed bitmasks: packedT[w*NN + n] holds bits
// for columns m = 32w..32w+31 of row n. Bits for m >= NN are 0.
// ---------------------------------------------------------------------------
__global__ void pack_adj_kernel(const int* __restrict__ adj,
                                unsigned int* __restrict__ packedT)
{
    int idx = blockIdx.x * 256 + threadIdx.x;
    if (idx >= 11 * NN) return;
    int w = idx / NN, n = idx - w * NN;
    unsigned int bits = 0u;
    #pragma unroll 8
    for (int j = 0; j < 32; ++j) {
        int m = w * 32 + j;
        if (m < NN && adj[n * NN + m] > 0) bits |= (1u << j);
    }
    packedT[w * NN + n] = bits;
}

// ---------------------------------------------------------------------------
// Kernel 1: q/k/v = gelu(concat(X,STE) @ W.T + b) via f16 MFMA.
// Outputs are f16 (q pre-scaled by SCL) — attn consumes f16 directly.
// ---------------------------------------------------------------------------
#define XS 136   // half stride per 128-k row (68 dwords)

__device__ __forceinline__ void qkv_mfma_phase(
    const half_t* x16, const half_t* w16p, const float* __restrict__ b,
    half_t* __restrict__ outp, float oscale,
    int row0, int rbase, int l15, int quad)
{
    float4_t acc[4];
    #pragma unroll
    for (int ct = 0; ct < 4; ++ct) {
        float bias = b[ct * 16 + l15];
        acc[ct] = (float4_t){bias, bias, bias, bias};
    }
    #pragma unroll
    for (int kk = 0; kk < 8; ++kk) {
        half4_t a = *(const half4_t*)&x16[(rbase + l15) * XS + kk * 16 + quad * 4];
        #pragma unroll
        for (int ct = 0; ct < 4; ++ct) {
            half4_t bf = *(const half4_t*)&w16p[(ct * 16 + l15) * XS + kk * 16 + quad * 4];
            acc[ct] = __builtin_amdgcn_mfma_f32_16x16x16f16(a, bf, acc[ct], 0, 0, 0);
        }
    }
    #pragma unroll
    for (int ct = 0; ct < 4; ++ct) {
        #pragma unroll
        for (int rr = 0; rr < 4; ++rr) {
            int R = row0 + rbase + quad * 4 + rr;
            if (R < NROWS)
                outp[R * 64 + ct * 16 + l15] =
                    (half_t)(gelu_f(acc[ct][rr]) * oscale);
        }
    }
}

__global__ __launch_bounds__(256) void qkv_kernel(
    const float* __restrict__ X, const float* __restrict__ STE,
    const float* __restrict__ W7, const float* __restrict__ b7,
    const float* __restrict__ W8, const float* __restrict__ b8,
    const float* __restrict__ W9, const float* __restrict__ b9,
    half_t* __restrict__ q, half_t* __restrict__ k, half_t* __restrict__ v)
{
    __shared__ __attribute__((aligned(16))) half_t x16[64 * XS];
    __shared__ __attribute__((aligned(16))) half_t w16[3][64 * XS];
    const int tid  = threadIdx.x;
    const int row0 = blockIdx.x * 64;

    #pragma unroll 2
    for (int idx = tid; idx < 64 * 32; idx += 256) {
        int r = idx >> 5, c4 = idx & 31;
        int R = row0 + r;
        float4 f = {0.f, 0.f, 0.f, 0.f};
        if (R < NROWS)
            f = (c4 < 16) ? *(const float4*)(X + R * 64 + c4 * 4)
                          : *(const float4*)(STE + R * 64 + (c4 - 16) * 4);
        half4_t hv;
        hv[0] = (half_t)f.x; hv[1] = (half_t)f.y;
        hv[2] = (half_t)f.z; hv[3] = (half_t)f.w;
        *(half4_t*)&x16[r * XS + c4 * 4] = hv;
    }
    #pragma unroll 2
    for (int idx = tid; idx < 3 * 64 * 32; idx += 256) {
        int p = idx >> 11, rem = idx & 2047;
        int c = rem >> 5, c4 = rem & 31;
        const float* Wp = (p == 0) ? W7 : (p == 1) ? W8 : W9;
        float4 f = *(const float4*)(Wp + c * 128 + c4 * 4);
        half4_t hv;
        hv[0] = (half_t)f.x; hv[1] = (half_t)f.y;
        hv[2] = (half_t)f.z; hv[3] = (half_t)f.w;
        *(half4_t*)&w16[p][c * XS + c4 * 4] = hv;
    }
    __syncthreads();

    const int lane = tid & 63, wv = tid >> 6;
    const int l15 = lane & 15, quad = lane >> 4;
    const int rbase = wv * 16;

    qkv_mfma_phase(x16, w16[0], b7, q, SCL, row0, rbase, l15, quad);
    qkv_mfma_phase(x16, w16[1], b8, k, 1.0f, row0, rbase, l15, quad);
    qkv_mfma_phase(x16, w16[2], b9, v, 1.0f, row0, rbase, l15, quad);
}

// ---------------------------------------------------------------------------
// Kernel 2: MFMA flash attention, f16 I/O.
//  - Q/K rows staged stride-20 halfs (d 8..15 zeroed; 2-way bank alias free)
//  - V staged TRANSPOSED via m-pair half2 writes (dword-granular,
//    consecutive banks -> no conflicts)
//  - mask words hoisted to 11 regs per n-tile straight from global
//    (packedT is L1/L2-resident; LDS drops to 38 KB -> 4 blocks/CU)
// ---------------------------------------------------------------------------
__global__ __launch_bounds__(256) void attn_kernel(
    const half_t* __restrict__ q16g, const half_t* __restrict__ k16g,
    const half_t* __restrict__ v16g, const unsigned int* __restrict__ packedT,
    half_t* __restrict__ ao)
{
    __shared__ __attribute__((aligned(16))) half_t Q16[336 * 20]; // [n][d0..15,pad]
    __shared__ __attribute__((aligned(16))) half_t K16[336 * 20]; // [m][d0..15,pad]
    __shared__ __attribute__((aligned(16))) half_t VT16[16 * 344];// [c][m]
    const int tid = threadIdx.x;
    const int h = blockIdx.x, bt = blockIdx.y;
    const long base = (long)(bt * NN) * 64 + h * 8;

    const half4_t z4 = {(half_t)0.f, (half_t)0.f, (half_t)0.f, (half_t)0.f};

    // stage Q/K rows (zero-fill rows >= NN and d 8..15)
    for (int r = tid; r < 336; r += 256) {
        half4_t qa = z4, qb = z4, ka = z4, kb = z4;
        if (r < NN) {
            qa = *(const half4_t*)(q16g + base + r * 64);
            qb = *(const half4_t*)(q16g + base + r * 64 + 4);
            ka = *(const half4_t*)(k16g + base + r * 64);
            kb = *(const half4_t*)(k16g + base + r * 64 + 4);
        }
        *(half4_t*)&Q16[r * 20]      = qa;
        *(half4_t*)&Q16[r * 20 + 4]  = qb;
        *(half4_t*)&Q16[r * 20 + 8]  = z4;
        *(half4_t*)&Q16[r * 20 + 12] = z4;
        *(half4_t*)&K16[r * 20]      = ka;
        *(half4_t*)&K16[r * 20 + 4]  = kb;
        *(half4_t*)&K16[r * 20 + 8]  = z4;
        *(half4_t*)&K16[r * 20 + 12] = z4;
    }

    // stage V transposed: thread mp handles m = 2mp, 2mp+1; dword writes
    for (int mp = tid; mp < 168; mp += 256) {
        int m0 = 2 * mp, m1 = 2 * mp + 1;
        half4_t v0a = z4, v0b = z4, v1a = z4, v1b = z4;
        if (m0 < NN) {
            v0a = *(const half4_t*)(v16g + base + m0 * 64);
            v0b = *(const half4_t*)(v16g + base + m0 * 64 + 4);
        }
        if (m1 < NN) {
            v1a = *(const half4_t*)(v16g + base + m1 * 64);
            v1b = *(const half4_t*)(v16g + base + m1 * 64 + 4);
        }
        #pragma unroll
        for (int c = 0; c < 4; ++c) {
            half2_t p0; p0[0] = v0a[c]; p0[1] = v1a[c];
            half2_t p1; p1[0] = v0b[c]; p1[1] = v1b[c];
            *(half2_t*)&VT16[c * 344 + 2 * mp]       = p0;
            *(half2_t*)&VT16[(c + 4) * 344 + 2 * mp] = p1;
        }
    }
    __syncthreads();

    const int lane = tid & 63;
    const int wv   = tid >> 6;
    const int l15  = lane & 15;
    const int quad = lane >> 4;
    const int qsh  = quad * 4;

    for (int t = wv; t < 21; t += 4) {
        const int n = t * 16 + l15;
        const half4_t qf = *(const half4_t*)&Q16[n * 20 + qsh];

        // hoist mask words for this n into registers (global, L1-hot)
        unsigned int mb[11];
        #pragma unroll
        for (int w = 0; w < 11; ++w) mb[w] = packedT[w * NN + n];

        // pass A: row max
        float rm = -3.0e38f;
        for (int mt = 0; mt < 21; ++mt) {
            half4_t kf = *(const half4_t*)&K16[(mt * 16 + l15) * 20 + qsh];
            float4_t s = __builtin_amdgcn_mfma_f32_16x16x16f16(
                kf, qf, (float4_t){0.f, 0.f, 0.f, 0.f}, 0, 0, 0);
            unsigned int sh = mb[mt >> 1] >> (((mt & 1) << 4) + qsh);
            rm = fmaxf(rm, (sh & 1u) ? s[0] : -3.0e38f);
            rm = fmaxf(rm, (sh & 2u) ? s[1] : -3.0e38f);
            rm = fmaxf(rm, (sh & 4u) ? s[2] : -3.0e38f);
            rm = fmaxf(rm, (sh & 8u) ? s[3] : -3.0e38f);
        }
        rm = fmaxf(rm, __shfl_xor(rm, 16, 64));
        rm = fmaxf(rm, __shfl_xor(rm, 32, 64));

        // pass B: p = exp2(s - rm) -> f16 -> PV MFMA
        float4_t acc = {0.f, 0.f, 0.f, 0.f};
        float sum = 0.f;
        for (int mt = 0; mt < 21; ++mt) {
            half4_t kf = *(const half4_t*)&K16[(mt * 16 + l15) * 20 + qsh];
            float4_t s = __builtin_amdgcn_mfma_f32_16x16x16f16(
                kf, qf, (float4_t){0.f, 0.f, 0.f, 0.f}, 0, 0, 0);
            unsigned int sh = mb[mt >> 1] >> (((mt & 1) << 4) + qsh);
            float p0 = (sh & 1u) ? __builtin_amdgcn_exp2f(s[0] - rm) : 0.f;
            float p1 = (sh & 2u) ? __builtin_amdgcn_exp2f(s[1] - rm) : 0.f;
            float p2 = (sh & 4u) ? __builtin_amdgcn_exp2f(s[2] - rm) : 0.f;
            float p3 = (sh & 8u) ? __builtin_amdgcn_exp2f(s[3] - rm) : 0.f;
            sum += (p0 + p1) + (p2 + p3);
            half4_t pf;
            pf[0] = (half_t)p0; pf[1] = (half_t)p1;
            pf[2] = (half_t)p2; pf[3] = (half_t)p3;
            half4_t vf = *(const half4_t*)&VT16[l15 * 344 + mt * 16 + qsh];
            acc = __builtin_amdgcn_mfma_f32_16x16x16f16(vf, pf, acc, 0, 0, 0);
        }
        sum += __shfl_xor(sum, 16, 64);
        sum += __shfl_xor(sum, 32, 64);

        if (quad < 2 && n < NN) {
            float inv = 1.0f / sum;
            half4_t o;
            o[0] = (half_t)(acc[0] * inv); o[1] = (half_t)(acc[1] * inv);
            o[2] = (half_t)(acc[2] * inv); o[3] = (half_t)(acc[3] * inv);
            *(half4_t*)(ao + base + n * 64 + qsh) = o;
        }
    }
}

// ---------------------------------------------------------------------------
// Kernel 3: out = gelu(ao @ W10.T + b10) @ W11.T + b11 via f16 MFMA.
// ao is f16 -> staging is a straight b128 copy.
// ---------------------------------------------------------------------------
#define PS 72   // half stride per 64-k row (36 dwords)

__global__ __launch_bounds__(256) void proj_kernel(
    const half_t* __restrict__ ao,
    const float* __restrict__ W10, const float* __restrict__ b10,
    const float* __restrict__ W11, const float* __restrict__ b11,
    float* __restrict__ out)
{
    __shared__ __attribute__((aligned(16))) half_t a16[64 * PS];
    __shared__ __attribute__((aligned(16))) half_t wA[64 * PS];
    __shared__ __attribute__((aligned(16))) half_t wB[64 * PS];
    __shared__ __attribute__((aligned(16))) half_t h16[64 * PS];
    const int tid  = threadIdx.x;
    const int row0 = blockIdx.x * 64;

    // a16: straight f16 copy (b128); weights: cvt f32->f16
    for (int idx = tid; idx < 64 * 8; idx += 256) {
        int r = idx >> 3, c8 = idx & 7;
        int R = row0 + r;
        uint4 u = {0u, 0u, 0u, 0u};
        if (R < NROWS) u = *(const uint4*)(ao + R * 64 + c8 * 8);
        *(uint4*)&a16[r * PS + c8 * 8] = u;
    }
    for (int idx = tid; idx < 64 * 16; idx += 256) {
        int r = idx >> 4, c4 = idx & 15;
        float4 fA = *(const float4*)(W10 + r * 64 + c4 * 4);
        float4 fB = *(const float4*)(W11 + r * 64 + c4 * 4);
        half4_t hA, hB;
        hA[0] = (half_t)fA.x; hA[1] = (half_t)fA.y;
        hA[2] = (half_t)fA.z; hA[3] = (half_t)fA.w;
        hB[0] = (half_t)fB.x; hB[1] = (half_t)fB.y;
        hB[2] = (half_t)fB.z; hB[3] = (half_t)fB.w;
        *(half4_t*)&wA[r * PS + c4 * 4] = hA;
        *(half4_t*)&wB[r * PS + c4 * 4] = hB;
    }
    __syncthreads();

    const int lane = tid & 63, wv = tid >> 6;
    const int l15 = lane & 15, quad = lane >> 4;
    const int rbase = wv * 16;

    float4_t acc[4];
    #pragma unroll
    for (int ct = 0; ct < 4; ++ct) {
        float bias = b10[ct * 16 + l15];
        acc[ct] = (float4_t){bias, bias, bias, bias};
    }
    #pragma unroll
    for (int kk = 0; kk < 4; ++kk) {
        half4_t a = *(const half4_t*)&a16[(rbase + l15) * PS + kk * 16 + quad * 4];
        #pragma unroll
        for (int ct = 0; ct < 4; ++ct) {
            half4_t bf = *(const half4_t*)&wA[(ct * 16 + l15) * PS + kk * 16 + quad * 4];
            acc[ct] = __builtin_amdgcn_mfma_f32_16x16x16f16(a, bf, acc[ct], 0, 0, 0);
        }
    }
    #pragma unroll
    for (int ct = 0; ct < 4; ++ct) {
        #pragma unroll
        for (int rr = 0; rr < 4; ++rr)
            h16[(rbase + quad * 4 + rr) * PS + ct * 16 + l15] =
                (half_t)gelu_f(acc[ct][rr]);
    }
    __syncthreads();

    #pragma unroll
    for (int ct = 0; ct < 4; ++ct) {
        float bias = b11[ct * 16 + l15];
        acc[ct] = (float4_t){bias, bias, bias, bias};
    }
    #pragma unroll
    for (int kk = 0; kk < 4; ++kk) {
        half4_t a = *(const half4_t*)&h16[(rbase + l15) * PS + kk * 16 + quad * 4];
        #pragma unroll
        for (int ct = 0; ct < 4; ++ct) {
            half4_t bf = *(const half4_t*)&wB[(ct * 16 + l15) * PS + kk * 16 + quad * 4];
            acc[ct] = __builtin_amdgcn_mfma_f32_16x16x16f16(a, bf, acc[ct], 0, 0, 0);
        }
    }
    #pragma unroll
    for (int ct = 0; ct < 4; ++ct) {
        #pragma unroll
        for (int rr = 0; rr < 4; ++rr) {
            int R = row0 + rbase + quad * 4 + rr;
            if (R < NROWS)
                out[R * 64 + ct * 16 + l15] = acc[ct][rr];
        }
    }
}

extern "C" void kernel_launch(void* const* d_in, const int* in_sizes, int n_in,
                              void* d_out, int out_size, void* d_ws, size_t ws_size,
                              hipStream_t stream) {
    const float* X   = (const float*)d_in[0];
    const float* STE = (const float*)d_in[1];
    const int*   adj = (const int*)d_in[2];
    const float* W7  = (const float*)d_in[3];
    const float* b7  = (const float*)d_in[4];
    const float* W8  = (const float*)d_in[5];
    const float* b8  = (const float*)d_in[6];
    const float* W9  = (const float*)d_in[7];
    const float* b9  = (const float*)d_in[8];
    const float* W10 = (const float*)d_in[9];
    const float* b10 = (const float*)d_in[10];
    const float* W11 = (const float*)d_in[11];
    const float* b11 = (const float*)d_in[12];

    half_t* hws = (half_t*)d_ws;
    const long S = (long)NROWS * 64;  // 1,996,800 elements
    half_t* qb = hws;
    half_t* kb = hws + S;
    half_t* vb = hws + 2 * S;
    half_t* ab = hws + 3 * S;
    unsigned int* pk = (unsigned int*)(hws + 4 * S);  // 8-byte aligned

    pack_adj_kernel<<<(11 * NN + 255) / 256, 256, 0, stream>>>(adj, pk);
    qkv_kernel<<<dim3((NROWS + 63) / 64), 256, 0, stream>>>(
        X, STE, W7, b7, W8, b8, W9, b9, qb, kb, vb);
    attn_kernel<<<dim3(8, BT), 256, 0, stream>>>(qb, kb, vb, pk, ab);
    proj_kernel<<<dim3((NROWS + 63) / 64), 256, 0, stream>>>(
        ab, W10, b10, W11, b11, (float*)d_out);
}

// Round 9
// 153.173 us; speedup vs baseline: 1.8590x; 1.0724x over previous
//
#include <hip/hip_runtime.h>
#include <math.h>

#define NN 325
#define BT 96
#define NROWS (BT * NN)   // 31200
// fold softmax scale and log2(e) into q: exp(s/sqrt8) == exp2(s * SCL)
#define SCL (0.35355339059327373f * 1.4426950408889634f)

typedef _Float16 half_t;
typedef half_t half4_t __attribute__((ext_vector_type(4)));
typedef half_t half2_t __attribute__((ext_vector_type(2)));
typedef float float4_t __attribute__((ext_vector_type(4)));

__device__ __forceinline__ float gelu_f(float x) {
    return 0.5f * x * (1.0f + erff(x * 0.70710678118654752f));
}

// ---------------------------------------------------------------------------
// Kernel 0 (prep): pack adj bitmasks + convert all 5 weight matrices to f16.
// ---------------------------------------------------------------------------
__global__ void prep_kernel(const int* __restrict__ adj,
                            const float* __restrict__ W7,
                            const float* __restrict__ W8,
                            const float* __restrict__ W9,
                            const float* __restrict__ W10,
                            const float* __restrict__ W11,
                            unsigned int* __restrict__ packedT,
                            half_t* __restrict__ w789,
                            half_t* __restrict__ wab)
{
    int idx = blockIdx.x * 256 + threadIdx.x;
    if (idx < 11 * NN) {
        int w = idx / NN, n = idx - w * NN;
        unsigned int bits = 0u;
        #pragma unroll 8
        for (int j = 0; j < 32; ++j) {
            int m = w * 32 + j;
            if (m < NN && adj[n * NN + m] > 0) bits |= (1u << j);
        }
        packedT[w * NN + n] = bits;
    } else if (idx < 3575 + 24576) {
        int i = idx - 3575;
        int p = i >> 13, r = i & 8191;
        const float* Wp = (p == 0) ? W7 : (p == 1) ? W8 : W9;
        w789[i] = (half_t)Wp[r];
    } else if (idx < 3575 + 24576 + 8192) {
        int i = idx - 28151;
        int p = i >> 12, r = i & 4095;
        wab[i] = (half_t)(p ? W11[r] : W10[r]);
    }
}

// ---------------------------------------------------------------------------
// Kernel 1: q/k/v = gelu(concat(X,STE) @ W.T + b) via f16 MFMA.
// 512 thr (8 waves): wave = (row-tile 0..3, col-half 0..1) -> 16 MFMA/phase.
// Weight LDS ping-pong: stage W(p+1) while computing phase p (52 KB -> 3/CU).
// ---------------------------------------------------------------------------
#define XS 136   // half stride per 128-k row

__device__ __forceinline__ void qkv_stage_w(const half_t* __restrict__ src,
                                            half_t* dst, int tid)
{
    #pragma unroll
    for (int idx = tid; idx < 1024; idx += 512) {
        int c = idx >> 4, g = idx & 15;
        *(uint4*)&dst[c * XS + g * 8] = *(const uint4*)&src[c * 128 + g * 8];
    }
}

__device__ __forceinline__ void qkv_compute(
    const half_t* x16, const half_t* wb, const float* __restrict__ b,
    half_t* __restrict__ outp, float oscale,
    int row0, int rbase, int ch, int l15, int quad)
{
    float4_t acc[2];
    #pragma unroll
    for (int cc = 0; cc < 2; ++cc) {
        float bias = b[(ch * 2 + cc) * 16 + l15];
        acc[cc] = (float4_t){bias, bias, bias, bias};
    }
    #pragma unroll
    for (int kk = 0; kk < 8; ++kk) {
        half4_t a = *(const half4_t*)&x16[(rbase + l15) * XS + kk * 16 + quad * 4];
        #pragma unroll
        for (int cc = 0; cc < 2; ++cc) {
            half4_t bf = *(const half4_t*)
                &wb[((ch * 2 + cc) * 16 + l15) * XS + kk * 16 + quad * 4];
            acc[cc] = __builtin_amdgcn_mfma_f32_16x16x16f16(a, bf, acc[cc], 0, 0, 0);
        }
    }
    #pragma unroll
    for (int cc = 0; cc < 2; ++cc) {
        #pragma unroll
        for (int rr = 0; rr < 4; ++rr) {
            int R = row0 + rbase + quad * 4 + rr;
            if (R < NROWS)
                outp[R * 64 + (ch * 2 + cc) * 16 + l15] =
                    (half_t)(gelu_f(acc[cc][rr]) * oscale);
        }
    }
}

__global__ __launch_bounds__(512) void qkv_kernel(
    const float* __restrict__ X, const float* __restrict__ STE,
    const half_t* __restrict__ w789,
    const float* __restrict__ b7, const float* __restrict__ b8,
    const float* __restrict__ b9,
    half_t* __restrict__ q, half_t* __restrict__ k, half_t* __restrict__ v)
{
    __shared__ __attribute__((aligned(16))) half_t x16[64 * XS];
    __shared__ __attribute__((aligned(16))) half_t wbuf[2][64 * XS];
    const int tid  = threadIdx.x;
    const int row0 = blockIdx.x * 64;

    // stage x = concat(X, STE) -> f16
    #pragma unroll
    for (int idx = tid; idx < 2048; idx += 512) {
        int r = idx >> 5, c4 = idx & 31;
        int R = row0 + r;
        float4 f = {0.f, 0.f, 0.f, 0.f};
        if (R < NROWS)
            f = (c4 < 16) ? *(const float4*)(X + R * 64 + c4 * 4)
                          : *(const float4*)(STE + R * 64 + (c4 - 16) * 4);
        half4_t hv;
        hv[0] = (half_t)f.x; hv[1] = (half_t)f.y;
        hv[2] = (half_t)f.z; hv[3] = (half_t)f.w;
        *(half4_t*)&x16[r * XS + c4 * 4] = hv;
    }
    qkv_stage_w(w789, wbuf[0], tid);          // W7
    __syncthreads();

    const int lane = tid & 63, wv = tid >> 6;
    const int l15 = lane & 15, quad = lane >> 4;
    const int rbase = (wv & 3) * 16, ch = wv >> 2;

    qkv_stage_w(w789 + 8192, wbuf[1], tid);   // W8 (overlaps phase 0)
    qkv_compute(x16, wbuf[0], b7, q, SCL, row0, rbase, ch, l15, quad);
    __syncthreads();

    qkv_stage_w(w789 + 16384, wbuf[0], tid);  // W9 (overlaps phase 1)
    qkv_compute(x16, wbuf[1], b8, k, 1.0f, row0, rbase, ch, l15, quad);
    __syncthreads();

    qkv_compute(x16, wbuf[0], b9, v, 1.0f, row0, rbase, ch, l15, quad);
}

// ---------------------------------------------------------------------------
// Kernel 2: MFMA flash attention v3.
//  - pass A: UNMASKED row max (e = exp2(s-rm) <= 1 always -> f16 safe)
//  - pass B: -rm folded into QK MFMA C-operand; sum via ones-row (VT row 8)
//  - Q read per-tile from global (quad>=2 predicated to zero) -> no Q LDS
//  - LDS 24.4 KB
// ---------------------------------------------------------------------------
__global__ __launch_bounds__(256) void attn_kernel(
    const half_t* __restrict__ q16g, const half_t* __restrict__ k16g,
    const half_t* __restrict__ v16g, const unsigned int* __restrict__ packedT,
    half_t* __restrict__ ao)
{
    __shared__ __attribute__((aligned(16))) half_t K16[336 * 20]; // [m][d0..15,pad]
    __shared__ __attribute__((aligned(16))) half_t VT16[16 * 344];// [c][m]
    const int tid = threadIdx.x;
    const int h = blockIdx.x, bt = blockIdx.y;
    const long base = (long)(bt * NN) * 64 + h * 8;

    const half4_t z4 = {(half_t)0.f, (half_t)0.f, (half_t)0.f, (half_t)0.f};

    // zero VT16, then ones row c=8
    for (int idx = tid; idx < 16 * 344 / 2; idx += 256)
        ((half2_t*)VT16)[idx] = (half2_t)(half_t)0.f;
    __syncthreads();
    for (int i = tid; i < 344; i += 256)
        VT16[8 * 344 + i] = (half_t)1.0f;

    // stage K rows (stride 20, d 8..15 zero)
    for (int r = tid; r < 336; r += 256) {
        half4_t ka = z4, kb = z4;
        if (r < NN) {
            ka = *(const half4_t*)(k16g + base + r * 64);
            kb = *(const half4_t*)(k16g + base + r * 64 + 4);
        }
        *(half4_t*)&K16[r * 20]      = ka;
        *(half4_t*)&K16[r * 20 + 4]  = kb;
        *(half4_t*)&K16[r * 20 + 8]  = z4;
        *(half4_t*)&K16[r * 20 + 12] = z4;
    }

    // stage V transposed via m-pair half2 writes (rows c = 0..7)
    for (int mp = tid; mp < 168; mp += 256) {
        int m0 = 2 * mp, m1 = 2 * mp + 1;
        half4_t v0a = z4, v0b = z4, v1a = z4, v1b = z4;
        if (m0 < NN) {
            v0a = *(const half4_t*)(v16g + base + m0 * 64);
            v0b = *(const half4_t*)(v16g + base + m0 * 64 + 4);
        }
        if (m1 < NN) {
            v1a = *(const half4_t*)(v16g + base + m1 * 64);
            v1b = *(const half4_t*)(v16g + base + m1 * 64 + 4);
        }
        #pragma unroll
        for (int c = 0; c < 4; ++c) {
            half2_t p0; p0[0] = v0a[c]; p0[1] = v1a[c];
            half2_t p1; p1[0] = v0b[c]; p1[1] = v1b[c];
            *(half2_t*)&VT16[c * 344 + 2 * mp]       = p0;
            *(half2_t*)&VT16[(c + 4) * 344 + 2 * mp] = p1;
        }
    }
    __syncthreads();

    const int lane = tid & 63;
    const int wv   = tid >> 6;
    const int l15  = lane & 15;
    const int quad = lane >> 4;
    const int qsh  = quad * 4;

    for (int t = wv; t < 21; t += 4) {
        const int n  = t * 16 + l15;
        const int nq = (n < NN) ? n : (NN - 1);   // clamp for global reads

        half4_t qf = z4;
        if (quad < 2)
            qf = *(const half4_t*)(q16g + base + (long)nq * 64 + qsh);

        // pass A: unmasked row max (>= all s; padded rows give s=0)
        float rm = 0.0f;
        #pragma unroll
        for (int mt = 0; mt < 21; ++mt) {
            half4_t kf = *(const half4_t*)&K16[(mt * 16 + l15) * 20 + qsh];
            float4_t s = __builtin_amdgcn_mfma_f32_16x16x16f16(
                kf, qf, (float4_t){0.f, 0.f, 0.f, 0.f}, 0, 0, 0);
            rm = fmaxf(rm, fmaxf(fmaxf(s[0], s[1]), fmaxf(s[2], s[3])));
        }
        rm = fmaxf(rm, __shfl_xor(rm, 16, 64));
        rm = fmaxf(rm, __shfl_xor(rm, 32, 64));

        // mask words for this row
        unsigned int mb[11];
        #pragma unroll
        for (int w = 0; w < 11; ++w) mb[w] = packedT[w * NN + nq];

        // pass B: s' = K.Q^T - rm (C-operand), p = exp2(s'), sum via ones-row
        const float4_t cinit = {-rm, -rm, -rm, -rm};
        float4_t acc = {0.f, 0.f, 0.f, 0.f};
        #pragma unroll
        for (int mt = 0; mt < 21; ++mt) {
            half4_t kf = *(const half4_t*)&K16[(mt * 16 + l15) * 20 + qsh];
            float4_t s = __builtin_amdgcn_mfma_f32_16x16x16f16(
                kf, qf, cinit, 0, 0, 0);
            unsigned int sh = mb[mt >> 1] >> (((mt & 1) << 4) + qsh);
            float p0 = (sh & 1u) ? __builtin_amdgcn_exp2f(s[0]) : 0.f;
            float p1 = (sh & 2u) ? __builtin_amdgcn_exp2f(s[1]) : 0.f;
            float p2 = (sh & 4u) ? __builtin_amdgcn_exp2f(s[2]) : 0.f;
            float p3 = (sh & 8u) ? __builtin_amdgcn_exp2f(s[3]) : 0.f;
            half4_t pf;
            pf[0] = (half_t)p0; pf[1] = (half_t)p1;
            pf[2] = (half_t)p2; pf[3] = (half_t)p3;
            half4_t vf = *(const half4_t*)&VT16[l15 * 344 + mt * 16 + qsh];
            acc = __builtin_amdgcn_mfma_f32_16x16x16f16(vf, pf, acc, 0, 0, 0);
        }

        // sum for row n lives in lane (quad=2).acc[0]  (ones row c=8)
        float sum = __shfl(acc[0], 32 + l15, 64);

        if (quad < 2 && n < NN) {
            float inv = 1.0f / sum;
            half4_t o;
            o[0] = (half_t)(acc[0] * inv); o[1] = (half_t)(acc[1] * inv);
            o[2] = (half_t)(acc[2] * inv); o[3] = (half_t)(acc[3] * inv);
            *(half4_t*)(ao + base + (long)n * 64 + qsh) = o;
        }
    }
}

// ---------------------------------------------------------------------------
// Kernel 3: out = gelu(ao @ W10.T + b10) @ W11.T + b11 via f16 MFMA.
// 512 thr (8 waves): wave = (row-tile, col-half) -> 8 MFMA/stage.
// ---------------------------------------------------------------------------
#define PS 72   // half stride per 64-k row

__global__ __launch_bounds__(512) void proj_kernel(
    const half_t* __restrict__ ao, const half_t* __restrict__ wab,
    const float* __restrict__ b10, const float* __restrict__ b11,
    float* __restrict__ out)
{
    __shared__ __attribute__((aligned(16))) half_t a16[64 * PS];
    __shared__ __attribute__((aligned(16))) half_t wA[64 * PS];
    __shared__ __attribute__((aligned(16))) half_t wB[64 * PS];
    __shared__ __attribute__((aligned(16))) half_t h16[64 * PS];
    const int tid  = threadIdx.x;
    const int row0 = blockIdx.x * 64;

    for (int idx = tid; idx < 512; idx += 512) {
        int r = idx >> 3, c8 = idx & 7;
        int R = row0 + r;
        uint4 u = {0u, 0u, 0u, 0u};
        if (R < NROWS) u = *(const uint4*)(ao + (long)R * 64 + c8 * 8);
        *(uint4*)&a16[r * PS + c8 * 8] = u;
        *(uint4*)&wA[r * PS + c8 * 8] = *(const uint4*)&wab[r * 64 + c8 * 8];
        *(uint4*)&wB[r * PS + c8 * 8] = *(const uint4*)&wab[4096 + r * 64 + c8 * 8];
    }
    __syncthreads();

    const int lane = tid & 63, wv = tid >> 6;
    const int l15 = lane & 15, quad = lane >> 4;
    const int rbase = (wv & 3) * 16, ch = wv >> 2;

    // stage 1: h = gelu(a @ W10.T + b10)
    float4_t acc[2];
    #pragma unroll
    for (int cc = 0; cc < 2; ++cc) {
        float bias = b10[(ch * 2 + cc) * 16 + l15];
        acc[cc] = (float4_t){bias, bias, bias, bias};
    }
    #pragma unroll
    for (int kk = 0; kk < 4; ++kk) {
        half4_t a = *(const half4_t*)&a16[(rbase + l15) * PS + kk * 16 + quad * 4];
        #pragma unroll
        for (int cc = 0; cc < 2; ++cc) {
            half4_t bf = *(const half4_t*)
                &wA[((ch * 2 + cc) * 16 + l15) * PS + kk * 16 + quad * 4];
            acc[cc] = __builtin_amdgcn_mfma_f32_16x16x16f16(a, bf, acc[cc], 0, 0, 0);
        }
    }
    #pragma unroll
    for (int cc = 0; cc < 2; ++cc) {
        #pragma unroll
        for (int rr = 0; rr < 4; ++rr)
            h16[(rbase + quad * 4 + rr) * PS + (ch * 2 + cc) * 16 + l15] =
                (half_t)gelu_f(acc[cc][rr]);
    }
    __syncthreads();

    // stage 2: out = h @ W11.T + b11
    #pragma unroll
    for (int cc = 0; cc < 2; ++cc) {
        float bias = b11[(ch * 2 + cc) * 16 + l15];
        acc[cc] = (float4_t){bias, bias, bias, bias};
    }
    #pragma unroll
    for (int kk = 0; kk < 4; ++kk) {
        half4_t a = *(const half4_t*)&h16[(rbase + l15) * PS + kk * 16 + quad * 4];
        #pragma unroll
        for (int cc = 0; cc < 2; ++cc) {
            half4_t bf = *(const half4_t*)
                &wB[((ch * 2 + cc) * 16 + l15) * PS + kk * 16 + quad * 4];
            acc[cc] = __builtin_amdgcn_mfma_f32_16x16x16f16(a, bf, acc[cc], 0, 0, 0);
        }
    }
    #pragma unroll
    for (int cc = 0; cc < 2; ++cc) {
        #pragma unroll
        for (int rr = 0; rr < 4; ++rr) {
            int R = row0 + rbase + quad * 4 + rr;
            if (R < NROWS)
                out[R * 64 + (ch * 2 + cc) * 16 + l15] = acc[cc][rr];
        }
    }
}

extern "C" void kernel_launch(void* const* d_in, const int* in_sizes, int n_in,
                              void* d_out, int out_size, void* d_ws, size_t ws_size,
                              hipStream_t stream) {
    const float* X   = (const float*)d_in[0];
    const float* STE = (const float*)d_in[1];
    const int*   adj = (const int*)d_in[2];
    const float* W7  = (const float*)d_in[3];
    const float* b7  = (const float*)d_in[4];
    const float* W8  = (const float*)d_in[5];
    const float* b8  = (const float*)d_in[6];
    const float* W9  = (const float*)d_in[7];
    const float* b9  = (const float*)d_in[8];
    const float* W10 = (const float*)d_in[9];
    const float* b10 = (const float*)d_in[10];
    const float* W11 = (const float*)d_in[11];
    const float* b11 = (const float*)d_in[12];

    char* wsb = (char*)d_ws;
    const long S = (long)NROWS * 64;           // 1,996,800 elements
    half_t* qb = (half_t*)wsb;
    half_t* kb = qb + S;
    half_t* vb = qb + 2 * S;
    half_t* ab = qb + 3 * S;
    unsigned int* pk = (unsigned int*)(wsb + 4 * S * sizeof(half_t));
    half_t* w789 = (half_t*)(wsb + 4 * S * sizeof(half_t) + 16384);
    half_t* wab  = w789 + 24576;

    prep_kernel<<<142, 256, 0, stream>>>(adj, W7, W8, W9, W10, W11,
                                         pk, w789, wab);
    qkv_kernel<<<dim3((NROWS + 63) / 64), 512, 0, stream>>>(
        X, STE, w789, b7, b8, b9, qb, kb, vb);
    attn_kernel<<<dim3(8, BT), 256, 0, stream>>>(qb, kb, vb, pk, ab);
    proj_kernel<<<dim3((NROWS + 63) / 64), 512, 0, stream>>>(
        ab, wab, b10, b11, (float*)d_out);
}